// Round 2
// baseline (1616.148 us; speedup 1.0000x reference)
//
#include <hip/hip_runtime.h>
#include <hip/hip_bf16.h>

// Swin block, B=8 H=W=128 C=192 HEADS=6 WS=8 SS=4 MLP_H=384
// tokens T = 131072, windows 2048 (256/batch), N=64, hd=32
// I/O dtype: float32 (per reference). Internal GEMM compute: bf16 MFMA
// (2% relative tolerance permits). Workspace intermediates: bf16.
//
// Pipeline:
//  1. ln1 + shift + window partition -> xw  [T,192] bf16   (ws)
//  2. qkv GEMM (mfma 16x16x32 bf16)  -> q,k,v [2048][6][64][32] bf16, q pre-scaled
//  3. attention (1 wave per win,head) -> attn_out [T,192] bf16 (reuses xw)
//  4. proj GEMM + unshift/reverse + residual -> x1 [T,192] f32 (stored in d_out)
//  5. ln2 -> xn2 bf16 (reuses xw) ; 6. fc1+gelu -> h1 [T,384] bf16 (reuses q+k)
//  7. fc2 + residual (reads x1 from d_out) -> out (d_out, in-place RMW)

typedef __hip_bfloat16 bf16;
typedef __bf16 bf16x8 __attribute__((ext_vector_type(8)));
typedef float f32x4 __attribute__((ext_vector_type(4)));

static __device__ __forceinline__ float bfr2f(unsigned int u) {
    union { unsigned int i; float f; } c; c.i = u << 16; return c.f;
}
static __device__ __forceinline__ bf16x8 ldg8(const bf16* p) {
    return *reinterpret_cast<const bf16x8*>(p);
}
static __device__ __forceinline__ void bf8_to_f(uint4 u, float* f) {
    f[0] = bfr2f(u.x & 0xffffu); f[1] = bfr2f(u.x >> 16);
    f[2] = bfr2f(u.y & 0xffffu); f[3] = bfr2f(u.y >> 16);
    f[4] = bfr2f(u.z & 0xffffu); f[5] = bfr2f(u.z >> 16);
    f[6] = bfr2f(u.w & 0xffffu); f[7] = bfr2f(u.w >> 16);
}

// B-fragment: 8 consecutive f32 of a weight row -> bf16x8
static __device__ __forceinline__ bf16x8 cvt8(const float* p) {
    float4 u0 = *reinterpret_cast<const float4*>(p);
    float4 u1 = *reinterpret_cast<const float4*>(p + 4);
    bf16x8 b;
    b[0] = (__bf16)u0.x; b[1] = (__bf16)u0.y; b[2] = (__bf16)u0.z; b[3] = (__bf16)u0.w;
    b[4] = (__bf16)u1.x; b[5] = (__bf16)u1.y; b[6] = (__bf16)u1.z; b[7] = (__bf16)u1.w;
    return b;
}

template <int KS>
static __device__ __forceinline__ f32x4 mfma_rowtile(const bf16x8* a, const float* wrow) {
    f32x4 acc = {0.f, 0.f, 0.f, 0.f};
#pragma unroll
    for (int kk = 0; kk < KS; ++kk) {
        bf16x8 b = cvt8(wrow + kk * 32);
        acc = __builtin_amdgcn_mfma_f32_16x16x32_bf16(a[kk], b, acc, 0, 0, 0);
    }
    return acc;
}

// ---------------- LN (+ optional shift+window gather), f32 in -> bf16 out ----------
// block 256 = 4 waves, one token per wave, 3 channels per lane (192 = 64*3)
__global__ __launch_bounds__(256) void ln_kernel(
    const float* __restrict__ x, const float* __restrict__ g,
    const float* __restrict__ bb, bf16* __restrict__ out, int windowed)
{
    int wave = threadIdx.x >> 6, lane = threadIdx.x & 63;
    int o = blockIdx.x * 4 + wave;          // output token (windowed order if windowed)
    size_t src;
    if (windowed) {
        int win = o >> 6, n = o & 63;
        int b = win >> 8, wrem = win & 255, wr = wrem >> 4, wc = wrem & 15;
        int i = n >> 3, j = n & 7;
        int h = (wr * 8 + i + 4) & 127, w = (wc * 8 + j + 4) & 127;
        src = (size_t)b * 16384 + h * 128 + w;
    } else {
        src = (size_t)o;
    }
    const float* xp = x + src * 192 + lane * 3;
    float v0 = xp[0], v1 = xp[1], v2 = xp[2];
    float sum = v0 + v1 + v2;
    float sq = v0 * v0 + v1 * v1 + v2 * v2;
#pragma unroll
    for (int off = 32; off; off >>= 1) {
        sum += __shfl_xor(sum, off, 64);
        sq  += __shfl_xor(sq, off, 64);
    }
    float mean = sum * (1.f / 192.f);
    float var = sq * (1.f / 192.f) - mean * mean;
    float rstd = rsqrtf(var + 1e-5f);
    int c = lane * 3;
    bf16* op = out + (size_t)o * 192 + c;
    op[0] = __float2bfloat16((v0 - mean) * rstd * g[c]     + bb[c]);
    op[1] = __float2bfloat16((v1 - mean) * rstd * g[c + 1] + bb[c + 1]);
    op[2] = __float2bfloat16((v2 - mean) * rstd * g[c + 2] + bb[c + 2]);
}

// ---------------- QKV GEMM: [T,192] @ [576,192]^T -> scatter q/k/v ----------------
__global__ __launch_bounds__(256) void qkv_gemm(
    const bf16* __restrict__ A, const float* __restrict__ W,
    const float* __restrict__ bias, bf16* __restrict__ q,
    bf16* __restrict__ k, bf16* __restrict__ v)
{
    int wave = threadIdx.x >> 6, lane = threadIdx.x & 63;
    int quad = lane >> 4, l16 = lane & 15;
    int mbase = blockIdx.x * 64 + wave * 16;
    bf16x8 a[6];
    const bf16* arow = A + (size_t)(mbase + l16) * 192 + quad * 8;
#pragma unroll
    for (int kk = 0; kk < 6; ++kk) a[kk] = ldg8(arow + kk * 32);
    for (int nt = 0; nt < 36; ++nt) {
        const float* wrow = W + (size_t)(nt * 16 + l16) * 192 + quad * 8;
        f32x4 acc = mfma_rowtile<6>(a, wrow);
        int f = nt * 16 + l16;
        float bb = bias[f];
        int which = f / 192;
        int head = (f % 192) >> 5;
        int d = f & 31;
        bf16* dst = (which == 0) ? q : ((which == 1) ? k : v);
        float sc = (which == 0) ? 0.17677669529663687f : 1.f;
#pragma unroll
        for (int r = 0; r < 4; ++r) {
            int m = mbase + quad * 4 + r;
            int win = m >> 6, n = m & 63;
            float val = (acc[r] + bb) * sc;
            dst[((size_t)(win * 6 + head) * 64 + n) * 32 + d] = __float2bfloat16(val);
        }
    }
}

// ---------------- Attention: one wave per (win, head) ----------------
__global__ __launch_bounds__(256, 1) void attn_kernel(
    const bf16* __restrict__ q, const bf16* __restrict__ k,
    const bf16* __restrict__ v, const float* __restrict__ rpb,
    const int* __restrict__ rel, const float* __restrict__ amask,
    bf16* __restrict__ out)
{
    __shared__ float Ksh[4][64][32];
    __shared__ float Vsh[4][64][32];
    int wave = threadIdx.x >> 6, lane = threadIdx.x & 63;
    int wh = blockIdx.x * 4 + wave;   // 0..12287
    int win = wh / 6, head = wh % 6;

    const uint4* kp = reinterpret_cast<const uint4*>(k + (size_t)wh * 2048) + lane * 4;
    const uint4* vp = reinterpret_cast<const uint4*>(v + (size_t)wh * 2048) + lane * 4;
    const uint4* qp = reinterpret_cast<const uint4*>(q + (size_t)wh * 2048) + lane * 4;
    float qr[32];
#pragma unroll
    for (int t = 0; t < 4; ++t) {
        float tmp[8];
        bf8_to_f(kp[t], tmp);
#pragma unroll
        for (int e = 0; e < 8; ++e) Ksh[wave][lane][t * 8 + e] = tmp[e];
        bf8_to_f(vp[t], tmp);
#pragma unroll
        for (int e = 0; e < 8; ++e) Vsh[wave][lane][t * 8 + e] = tmp[e];
        bf8_to_f(qp[t], qr + t * 8);
    }
    __syncthreads();

    // lane == query token n
    float s[64];
    float mx = -3.4e38f;
    const int* ri = rel + lane * 64;
    const float* mrow = amask + (size_t)(win & 255) * 4096 + (size_t)lane * 64;
    for (int j = 0; j < 64; ++j) {
        const float* kj = Ksh[wave][j];
        float dot = 0.f;
#pragma unroll
        for (int d = 0; d < 32; ++d) dot += qr[d] * kj[d];
        dot += rpb[ri[j] * 6 + head];
        dot += mrow[j];
        s[j] = dot;
        mx = fmaxf(mx, dot);
    }
    float l = 0.f;
    float acc[32];
#pragma unroll
    for (int d = 0; d < 32; ++d) acc[d] = 0.f;
    for (int j = 0; j < 64; ++j) {
        float p = __expf(s[j] - mx);
        l += p;
        const float* vj = Vsh[wave][j];
#pragma unroll
        for (int d = 0; d < 32; ++d) acc[d] += p * vj[d];
    }
    float inv = 1.f / l;
    bf16* ob = out + ((size_t)win * 64 + lane) * 192 + head * 32;
#pragma unroll
    for (int d = 0; d < 32; ++d) ob[d] = __float2bfloat16(acc[d] * inv);
}

// ------------- Proj GEMM + window-reverse + unshift + residual -> x1 (f32) -------------
__global__ __launch_bounds__(256) void proj_gemm(
    const bf16* __restrict__ A, const float* __restrict__ W,
    const float* __restrict__ bias, const float* __restrict__ x0,
    float* __restrict__ x1)
{
    int wave = threadIdx.x >> 6, lane = threadIdx.x & 63;
    int quad = lane >> 4, l16 = lane & 15;
    int mbase = blockIdx.x * 64 + wave * 16;
    bf16x8 a[6];
    const bf16* arow = A + (size_t)(mbase + l16) * 192 + quad * 8;
#pragma unroll
    for (int kk = 0; kk < 6; ++kk) a[kk] = ldg8(arow + kk * 32);
    for (int nt = 0; nt < 12; ++nt) {
        const float* wrow = W + (size_t)(nt * 16 + l16) * 192 + quad * 8;
        f32x4 acc = mfma_rowtile<6>(a, wrow);
        int c = nt * 16 + l16;
        float bb = bias[c];
#pragma unroll
        for (int r = 0; r < 4; ++r) {
            int m = mbase + quad * 4 + r;
            int win = m >> 6, n = m & 63;
            int b = win >> 8, wrem = win & 255, wr = wrem >> 4, wc = wrem & 15;
            int i = n >> 3, j = n & 7;
            int h = (wr * 8 + i + 4) & 127, w = (wc * 8 + j + 4) & 127;
            size_t sidx = ((size_t)b * 16384 + h * 128 + w) * 192 + c;
            x1[sidx] = acc[r] + bb + x0[sidx];
        }
    }
}

// ---------------- FC1 GEMM + exact GELU: [T,192] @ [384,192]^T -> h1 bf16 -------------
__global__ __launch_bounds__(256) void fc1_gemm(
    const bf16* __restrict__ A, const float* __restrict__ W,
    const float* __restrict__ bias, bf16* __restrict__ h1)
{
    int wave = threadIdx.x >> 6, lane = threadIdx.x & 63;
    int quad = lane >> 4, l16 = lane & 15;
    int mbase = blockIdx.x * 64 + wave * 16;
    bf16x8 a[6];
    const bf16* arow = A + (size_t)(mbase + l16) * 192 + quad * 8;
#pragma unroll
    for (int kk = 0; kk < 6; ++kk) a[kk] = ldg8(arow + kk * 32);
    for (int nt = 0; nt < 24; ++nt) {
        const float* wrow = W + (size_t)(nt * 16 + l16) * 192 + quad * 8;
        f32x4 acc = mfma_rowtile<6>(a, wrow);
        int c = nt * 16 + l16;
        float bb = bias[c];
#pragma unroll
        for (int r = 0; r < 4; ++r) {
            int m = mbase + quad * 4 + r;
            float val = acc[r] + bb;
            float gl = 0.5f * val * (1.f + erff(val * 0.70710678118654752f));
            h1[(size_t)m * 384 + c] = __float2bfloat16(gl);
        }
    }
}

// ---------------- FC2 GEMM + residual: [T,384] @ [192,384]^T -> out f32 ----------------
__global__ __launch_bounds__(256) void fc2_gemm(
    const bf16* __restrict__ A, const float* __restrict__ W,
    const float* __restrict__ bias, const float* __restrict__ x1,
    float* __restrict__ out)
{
    int wave = threadIdx.x >> 6, lane = threadIdx.x & 63;
    int quad = lane >> 4, l16 = lane & 15;
    int mbase = blockIdx.x * 64 + wave * 16;
    bf16x8 a[12];
    const bf16* arow = A + (size_t)(mbase + l16) * 384 + quad * 8;
#pragma unroll
    for (int kk = 0; kk < 12; ++kk) a[kk] = ldg8(arow + kk * 32);
    for (int nt = 0; nt < 12; ++nt) {
        const float* wrow = W + (size_t)(nt * 16 + l16) * 384 + quad * 8;
        f32x4 acc = mfma_rowtile<12>(a, wrow);
        int c = nt * 16 + l16;
        float bb = bias[c];
#pragma unroll
        for (int r = 0; r < 4; ++r) {
            int m = mbase + quad * 4 + r;
            size_t idx = (size_t)m * 192 + c;
            out[idx] = acc[r] + bb + x1[idx];   // same-index RMW, safe in-place
        }
    }
}

extern "C" void kernel_launch(void* const* d_in, const int* in_sizes, int n_in,
                              void* d_out, int out_size, void* d_ws, size_t ws_size,
                              hipStream_t stream)
{
    const float* x     = (const float*)d_in[0];
    const float* n1g   = (const float*)d_in[1];
    const float* n1b   = (const float*)d_in[2];
    const float* qkvw  = (const float*)d_in[3];
    const float* qkvb  = (const float*)d_in[4];
    const float* rpb   = (const float*)d_in[5];
    const float* projw = (const float*)d_in[6];
    const float* projb = (const float*)d_in[7];
    const float* n2g   = (const float*)d_in[8];
    const float* n2b   = (const float*)d_in[9];
    const float* fc1w  = (const float*)d_in[10];
    const float* fc1b  = (const float*)d_in[11];
    const float* fc2w  = (const float*)d_in[12];
    const float* fc2b  = (const float*)d_in[13];
    const int*   rel   = (const int*)d_in[14];
    const float* amask = (const float*)d_in[15];
    float* out = (float*)d_out;

    char* ws = (char*)d_ws;
    const size_t SZ = (size_t)131072 * 192 * 2;  // 50,331,648 B (bf16 [T,192])
    bf16* xw = (bf16*)(ws);            // ln1 out; then attn_out; then xn2
    bf16* qb = (bf16*)(ws + SZ);       // q; later h1 low half
    bf16* kb = (bf16*)(ws + 2 * SZ);   // k; later h1 high half
    bf16* vb = (bf16*)(ws + 3 * SZ);   // v
    bf16* xn2 = xw;
    bf16* h1  = qb;                    // [T,384] bf16 spans qb+kb
    float* x1 = out;                   // pre-MLP residual lives in d_out

    ln_kernel<<<32768, 256, 0, stream>>>(x, n1g, n1b, xw, 1);
    qkv_gemm<<<2048, 256, 0, stream>>>(xw, qkvw, qkvb, qb, kb, vb);
    attn_kernel<<<3072, 256, 0, stream>>>(qb, kb, vb, rpb, rel, amask, xw);
    proj_gemm<<<2048, 256, 0, stream>>>(xw, projw, projb, x, x1);
    ln_kernel<<<32768, 256, 0, stream>>>(x1, n2g, n2b, xn2, 0);
    fc1_gemm<<<2048, 256, 0, stream>>>(xn2, fc1w, fc1b, h1);
    fc2_gemm<<<2048, 256, 0, stream>>>(h1, fc2w, fc2b, x1, out);
}

// Round 3
// 810.496 us; speedup vs baseline: 1.9940x; 1.9940x over previous
//
#include <hip/hip_runtime.h>
#include <hip/hip_bf16.h>

// Swin block, B=8 H=W=128 C=192 HEADS=6 WS=8 SS=4 MLP_H=384
// T = 131072 tokens, 2048 windows (256/batch), N=64, hd=32. I/O f32.
//
// r3: bf16 weights (pre-converted), register-resident A-frag GEMMs,
//     MFMA attention (S^T = K.Q^T, LDS round-trip for P, V stored transposed),
//     fused bias+mask table bmT.

typedef __hip_bfloat16 bf16;
typedef __bf16 bf16x8 __attribute__((ext_vector_type(8)));
typedef float f32x4 __attribute__((ext_vector_type(4)));

static __device__ __forceinline__ bf16x8 ldg8(const bf16* p) {
    return *reinterpret_cast<const bf16x8*>(p);
}

// ---------------- f32 -> bf16 weight convert ----------------
__global__ __launch_bounds__(256) void cvt_kernel(
    const float* __restrict__ src, bf16* __restrict__ dst, int n)
{
    int i = (blockIdx.x * 256 + threadIdx.x) * 4;
    if (i < n) {
        float4 v = *reinterpret_cast<const float4*>(src + i);
        dst[i]     = __float2bfloat16(v.x);
        dst[i + 1] = __float2bfloat16(v.y);
        dst[i + 2] = __float2bfloat16(v.z);
        dst[i + 3] = __float2bfloat16(v.w);
    }
}

// ---------------- fused bias+mask table, TRANSPOSED: bmT[wm][head][n_k][n_q] ----
__global__ __launch_bounds__(256) void bm_kernel(
    const float* __restrict__ rpb, const int* __restrict__ rel,
    const float* __restrict__ amask, bf16* __restrict__ bmT)
{
    int wm = blockIdx.x / 6, head = blockIdx.x % 6;
    const float* mrow = amask + (size_t)wm * 4096;
    bf16* o = bmT + (size_t)blockIdx.x * 4096;
    for (int idx = threadIdx.x; idx < 4096; idx += 256) {
        int nk = idx >> 6, nq = idx & 63;
        int t = nq * 64 + nk;   // source is [query][key]
        o[idx] = __float2bfloat16(rpb[rel[t] * 6 + head] + mrow[t]);
    }
}

// ---------------- LN (+ optional shift+window gather), f32 in -> bf16 out ----------
__global__ __launch_bounds__(256) void ln_kernel(
    const float* __restrict__ x, const float* __restrict__ g,
    const float* __restrict__ bb, bf16* __restrict__ out, int windowed)
{
    int wave = threadIdx.x >> 6, lane = threadIdx.x & 63;
    int o = blockIdx.x * 4 + wave;
    size_t src;
    if (windowed) {
        int win = o >> 6, n = o & 63;
        int b = win >> 8, wrem = win & 255, wr = wrem >> 4, wc = wrem & 15;
        int i = n >> 3, j = n & 7;
        int h = (wr * 8 + i + 4) & 127, w = (wc * 8 + j + 4) & 127;
        src = (size_t)b * 16384 + h * 128 + w;
    } else {
        src = (size_t)o;
    }
    const float* xp = x + src * 192 + lane * 3;
    float v0 = xp[0], v1 = xp[1], v2 = xp[2];
    float sum = v0 + v1 + v2;
    float sq = v0 * v0 + v1 * v1 + v2 * v2;
#pragma unroll
    for (int off = 32; off; off >>= 1) {
        sum += __shfl_xor(sum, off, 64);
        sq  += __shfl_xor(sq, off, 64);
    }
    float mean = sum * (1.f / 192.f);
    float var = sq * (1.f / 192.f) - mean * mean;
    float rstd = rsqrtf(var + 1e-5f);
    int c = lane * 3;
    bf16* op = out + (size_t)o * 192 + c;
    op[0] = __float2bfloat16((v0 - mean) * rstd * g[c]     + bb[c]);
    op[1] = __float2bfloat16((v1 - mean) * rstd * g[c + 1] + bb[c + 1]);
    op[2] = __float2bfloat16((v2 - mean) * rstd * g[c + 2] + bb[c + 2]);
}

// ---------------- QKV GEMM: [T,192] @ [576,192]^T -> q,k [wh][n][d], vT [wh][d][n] ----
// block 256 = 4 waves, 64 rows per block; wave owns 9 of 36 n-tiles.
__global__ __launch_bounds__(256) void qkv_gemm(
    const bf16* __restrict__ A, const bf16* __restrict__ W,
    const float* __restrict__ bias, bf16* __restrict__ q,
    bf16* __restrict__ k, bf16* __restrict__ vt)
{
    int wave = threadIdx.x >> 6, lane = threadIdx.x & 63;
    int quad = lane >> 4, l16 = lane & 15;
    int win = blockIdx.x;
    int mbase = win * 64;
    bf16x8 a[4][6];
#pragma unroll
    for (int mt = 0; mt < 4; ++mt) {
        const bf16* ar = A + (size_t)(mbase + mt * 16 + l16) * 192 + quad * 8;
#pragma unroll
        for (int kk = 0; kk < 6; ++kk) a[mt][kk] = ldg8(ar + kk * 32);
    }
#pragma unroll 1
    for (int i = 0; i < 9; ++i) {
        int nt = wave * 9 + i;
        const bf16* wr = W + (size_t)(nt * 16 + l16) * 192 + quad * 8;
        bf16x8 b[6];
#pragma unroll
        for (int kk = 0; kk < 6; ++kk) b[kk] = ldg8(wr + kk * 32);
        f32x4 acc[4];
#pragma unroll
        for (int mt = 0; mt < 4; ++mt) {
            f32x4 z = {0.f, 0.f, 0.f, 0.f};
#pragma unroll
            for (int kk = 0; kk < 6; ++kk)
                z = __builtin_amdgcn_mfma_f32_16x16x32_bf16(a[mt][kk], b[kk], z, 0, 0, 0);
            acc[mt] = z;
        }
        int f = nt * 16 + l16;
        float bb = bias[f];
        int which = f / 192;
        int head = (f % 192) >> 5;
        int d = f & 31;
        float sc = (which == 0) ? 0.17677669529663687f : 1.f;
        size_t wh2 = (size_t)(win * 6 + head) * 2048;
#pragma unroll
        for (int mt = 0; mt < 4; ++mt) {
#pragma unroll
            for (int r = 0; r < 4; ++r) {
                int n = mt * 16 + quad * 4 + r;
                bf16 val = __float2bfloat16((acc[mt][r] + bb) * sc);
                if (which == 2)      vt[wh2 + d * 64 + n] = val;
                else if (which == 1) k[wh2 + n * 32 + d] = val;
                else                 q[wh2 + n * 32 + d] = val;
            }
        }
    }
}

// ---------------- Attention (MFMA): one wave per (win, head) ----------------
// S^T = K.Q^T (rows=n_k, cols=n_q); softmax over rows; P -> LDS; O = P.V.
__global__ __launch_bounds__(256) void attn_kernel(
    const bf16* __restrict__ q, const bf16* __restrict__ k,
    const bf16* __restrict__ vt, const bf16* __restrict__ bmT,
    bf16* __restrict__ out)
{
    __shared__ __align__(16) bf16 lds[4][64 * 72];
    int wave = threadIdx.x >> 6, lane = threadIdx.x & 63;
    int quad = lane >> 4, l16 = lane & 15;
    int wh = blockIdx.x * 4 + wave;
    int win = wh / 6, head = wh - win * 6;
    const bf16* Qp = q + (size_t)wh * 2048;
    const bf16* Kp = k + (size_t)wh * 2048;
    const bf16* Vp = vt + (size_t)wh * 2048;
    const bf16* bm = bmT + (size_t)((win & 255) * 6 + head) * 4096;

    bf16x8 kf[4], qf[4];
#pragma unroll
    for (int t = 0; t < 4; ++t) {
        kf[t] = ldg8(Kp + (t * 16 + l16) * 32 + quad * 8);
        qf[t] = ldg8(Qp + (t * 16 + l16) * 32 + quad * 8);
    }
    f32x4 s[4][4];
#pragma unroll
    for (int mt = 0; mt < 4; ++mt)
#pragma unroll
        for (int nt = 0; nt < 4; ++nt) {
            f32x4 z = {0.f, 0.f, 0.f, 0.f};
            s[mt][nt] = __builtin_amdgcn_mfma_f32_16x16x32_bf16(kf[mt], qf[nt], z, 0, 0, 0);
        }
    // + bias + mask (transposed table; row nk = mt*16+quad*4+r, col nq = nt*16+l16)
#pragma unroll
    for (int mt = 0; mt < 4; ++mt)
#pragma unroll
        for (int nt = 0; nt < 4; ++nt)
#pragma unroll
            for (int r = 0; r < 4; ++r) {
                int nk = mt * 16 + quad * 4 + r, nq = nt * 16 + l16;
                s[mt][nt][r] += __bfloat162float(bm[nk * 64 + nq]);
            }
    // softmax over rows (n_k) per column
    float linv[4];
#pragma unroll
    for (int nt = 0; nt < 4; ++nt) {
        float mx = -3.0e38f;
#pragma unroll
        for (int mt = 0; mt < 4; ++mt)
#pragma unroll
            for (int r = 0; r < 4; ++r) mx = fmaxf(mx, s[mt][nt][r]);
        mx = fmaxf(mx, __shfl_xor(mx, 16, 64));
        mx = fmaxf(mx, __shfl_xor(mx, 32, 64));
        float sum = 0.f;
#pragma unroll
        for (int mt = 0; mt < 4; ++mt)
#pragma unroll
            for (int r = 0; r < 4; ++r) {
                float p = __expf(s[mt][nt][r] - mx);
                s[mt][nt][r] = p;
                sum += p;
            }
        sum += __shfl_xor(sum, 16, 64);
        sum += __shfl_xor(sum, 32, 64);
        linv[nt] = 1.f / sum;
    }
    // write P[n_q][n_k] to LDS (stride 72)
    bf16* lp = lds[wave];
#pragma unroll
    for (int mt = 0; mt < 4; ++mt)
#pragma unroll
        for (int nt = 0; nt < 4; ++nt)
#pragma unroll
            for (int r = 0; r < 4; ++r)
                lp[(nt * 16 + l16) * 72 + mt * 16 + quad * 4 + r] =
                    __float2bfloat16(s[mt][nt][r]);
    // O = P.V : A-frags of P from LDS, B-frags of V from vT (direct loads)
    f32x4 o[4][2];
#pragma unroll
    for (int mo = 0; mo < 4; ++mo)
#pragma unroll
        for (int no = 0; no < 2; ++no) o[mo][no] = (f32x4){0.f, 0.f, 0.f, 0.f};
#pragma unroll
    for (int kh = 0; kh < 2; ++kh) {
        bf16x8 pf[4];
#pragma unroll
        for (int mo = 0; mo < 4; ++mo)
            pf[mo] = *reinterpret_cast<const bf16x8*>(
                lp + (mo * 16 + l16) * 72 + kh * 32 + quad * 8);
#pragma unroll
        for (int no = 0; no < 2; ++no) {
            bf16x8 vf = ldg8(Vp + (no * 16 + l16) * 64 + kh * 32 + quad * 8);
#pragma unroll
            for (int mo = 0; mo < 4; ++mo)
                o[mo][no] = __builtin_amdgcn_mfma_f32_16x16x32_bf16(pf[mo], vf, o[mo][no], 0, 0, 0);
        }
    }
    // normalize rows (n_q) and store
#pragma unroll
    for (int mo = 0; mo < 4; ++mo)
#pragma unroll
        for (int r = 0; r < 4; ++r) {
            int nq = mo * 16 + quad * 4 + r;
            float il = __shfl(linv[mo], quad * 4 + r, 64);
            bf16* ob = out + ((size_t)win * 64 + nq) * 192 + head * 32 + l16;
            ob[0]  = __float2bfloat16(o[mo][0][r] * il);
            ob[16] = __float2bfloat16(o[mo][1][r] * il);
        }
}

// ------------- Proj GEMM + window-reverse + unshift + residual -> x1 (f32) -------------
__global__ __launch_bounds__(256) void proj_gemm(
    const bf16* __restrict__ A, const bf16* __restrict__ W,
    const float* __restrict__ bias, const float* __restrict__ x0,
    float* __restrict__ x1)
{
    int wave = threadIdx.x >> 6, lane = threadIdx.x & 63;
    int quad = lane >> 4, l16 = lane & 15;
    int win = blockIdx.x;
    int mbase = win * 64;
    bf16x8 a[4][6];
#pragma unroll
    for (int mt = 0; mt < 4; ++mt) {
        const bf16* ar = A + (size_t)(mbase + mt * 16 + l16) * 192 + quad * 8;
#pragma unroll
        for (int kk = 0; kk < 6; ++kk) a[mt][kk] = ldg8(ar + kk * 32);
    }
    int b = win >> 8, wrem = win & 255, wr = wrem >> 4, wc = wrem & 15;
#pragma unroll 1
    for (int i = 0; i < 3; ++i) {
        int nt = wave * 3 + i;
        const bf16* wp = W + (size_t)(nt * 16 + l16) * 192 + quad * 8;
        bf16x8 bfr[6];
#pragma unroll
        for (int kk = 0; kk < 6; ++kk) bfr[kk] = ldg8(wp + kk * 32);
        int c = nt * 16 + l16;
        float bb = bias[c];
#pragma unroll
        for (int mt = 0; mt < 4; ++mt) {
            f32x4 z = {0.f, 0.f, 0.f, 0.f};
#pragma unroll
            for (int kk = 0; kk < 6; ++kk)
                z = __builtin_amdgcn_mfma_f32_16x16x32_bf16(a[mt][kk], bfr[kk], z, 0, 0, 0);
#pragma unroll
            for (int r = 0; r < 4; ++r) {
                int n = mt * 16 + quad * 4 + r;
                int ii = n >> 3, jj = n & 7;
                int h = (wr * 8 + ii + 4) & 127, w = (wc * 8 + jj + 4) & 127;
                size_t sidx = ((size_t)b * 16384 + h * 128 + w) * 192 + c;
                x1[sidx] = z[r] + bb + x0[sidx];
            }
        }
    }
}

// ---------------- FC1 GEMM + exact GELU -> h1 bf16 [T,384] ----------------
__global__ __launch_bounds__(256) void fc1_gemm(
    const bf16* __restrict__ A, const bf16* __restrict__ W,
    const float* __restrict__ bias, bf16* __restrict__ h1)
{
    int wave = threadIdx.x >> 6, lane = threadIdx.x & 63;
    int quad = lane >> 4, l16 = lane & 15;
    int mbase = blockIdx.x * 64;
    bf16x8 a[4][6];
#pragma unroll
    for (int mt = 0; mt < 4; ++mt) {
        const bf16* ar = A + (size_t)(mbase + mt * 16 + l16) * 192 + quad * 8;
#pragma unroll
        for (int kk = 0; kk < 6; ++kk) a[mt][kk] = ldg8(ar + kk * 32);
    }
#pragma unroll 1
    for (int i = 0; i < 6; ++i) {
        int nt = wave * 6 + i;
        const bf16* wp = W + (size_t)(nt * 16 + l16) * 192 + quad * 8;
        bf16x8 b[6];
#pragma unroll
        for (int kk = 0; kk < 6; ++kk) b[kk] = ldg8(wp + kk * 32);
        int c = nt * 16 + l16;
        float bb = bias[c];
#pragma unroll
        for (int mt = 0; mt < 4; ++mt) {
            f32x4 z = {0.f, 0.f, 0.f, 0.f};
#pragma unroll
            for (int kk = 0; kk < 6; ++kk)
                z = __builtin_amdgcn_mfma_f32_16x16x32_bf16(a[mt][kk], b[kk], z, 0, 0, 0);
#pragma unroll
            for (int r = 0; r < 4; ++r) {
                int m = mbase + mt * 16 + quad * 4 + r;
                float val = z[r] + bb;
                float gl = 0.5f * val * (1.f + erff(val * 0.70710678118654752f));
                h1[(size_t)m * 384 + c] = __float2bfloat16(gl);
            }
        }
    }
}

// ---------------- FC2 GEMM + residual -> out f32 ----------------
__global__ __launch_bounds__(256) void fc2_gemm(
    const bf16* __restrict__ A, const bf16* __restrict__ W,
    const float* __restrict__ bias, const float* __restrict__ x1,
    float* __restrict__ out)
{
    int wave = threadIdx.x >> 6, lane = threadIdx.x & 63;
    int quad = lane >> 4, l16 = lane & 15;
    int mbase = blockIdx.x * 64;
    f32x4 acc[3][4];
#pragma unroll
    for (int i = 0; i < 3; ++i)
#pragma unroll
        for (int mt = 0; mt < 4; ++mt) acc[i][mt] = (f32x4){0.f, 0.f, 0.f, 0.f};
#pragma unroll 1
    for (int kh = 0; kh < 2; ++kh) {
        bf16x8 a[4][6];
#pragma unroll
        for (int mt = 0; mt < 4; ++mt) {
            const bf16* ar = A + (size_t)(mbase + mt * 16 + l16) * 384 + kh * 192 + quad * 8;
#pragma unroll
            for (int kk = 0; kk < 6; ++kk) a[mt][kk] = ldg8(ar + kk * 32);
        }
#pragma unroll 1
        for (int i = 0; i < 3; ++i) {
            int nt = wave * 3 + i;
            const bf16* wp = W + (size_t)(nt * 16 + l16) * 384 + kh * 192 + quad * 8;
            bf16x8 b[6];
#pragma unroll
            for (int kk = 0; kk < 6; ++kk) b[kk] = ldg8(wp + kk * 32);
#pragma unroll
            for (int mt = 0; mt < 4; ++mt)
#pragma unroll
                for (int kk = 0; kk < 6; ++kk)
                    acc[i][mt] = __builtin_amdgcn_mfma_f32_16x16x32_bf16(a[mt][kk], b[kk], acc[i][mt], 0, 0, 0);
        }
    }
#pragma unroll
    for (int i = 0; i < 3; ++i) {
        int nt = wave * 3 + i;
        int c = nt * 16 + l16;
        float bb = bias[c];
#pragma unroll
        for (int mt = 0; mt < 4; ++mt)
#pragma unroll
            for (int r = 0; r < 4; ++r) {
                int m = mbase + mt * 16 + quad * 4 + r;
                size_t idx = (size_t)m * 192 + c;
                out[idx] = acc[i][mt][r] + bb + x1[idx];
            }
    }
}

extern "C" void kernel_launch(void* const* d_in, const int* in_sizes, int n_in,
                              void* d_out, int out_size, void* d_ws, size_t ws_size,
                              hipStream_t stream)
{
    const float* x     = (const float*)d_in[0];
    const float* n1g   = (const float*)d_in[1];
    const float* n1b   = (const float*)d_in[2];
    const float* qkvw  = (const float*)d_in[3];
    const float* qkvb  = (const float*)d_in[4];
    const float* rpb   = (const float*)d_in[5];
    const float* projw = (const float*)d_in[6];
    const float* projb = (const float*)d_in[7];
    const float* n2g   = (const float*)d_in[8];
    const float* n2b   = (const float*)d_in[9];
    const float* fc1w  = (const float*)d_in[10];
    const float* fc1b  = (const float*)d_in[11];
    const float* fc2w  = (const float*)d_in[12];
    const float* fc2b  = (const float*)d_in[13];
    const int*   rel   = (const int*)d_in[14];
    const float* amask = (const float*)d_in[15];
    float* out = (float*)d_out;

    char* ws = (char*)d_ws;
    const size_t SZ = (size_t)131072 * 192 * 2;  // 50,331,648 B
    bf16* xw = (bf16*)(ws);            // ln1 out -> attn_out -> xn2
    bf16* qb = (bf16*)(ws + SZ);
    bf16* kb = (bf16*)(ws + 2 * SZ);
    bf16* vtb = (bf16*)(ws + 3 * SZ);  // V transposed [wh][32][64]
    bf16* wq = (bf16*)(ws + 4 * SZ);               // 110592
    bf16* wp = wq + 110592;                         // 36864
    bf16* w1 = wp + 36864;                          // 73728
    bf16* w2 = w1 + 73728;                          // 73728
    bf16* bmT = w2 + 73728;                         // 6,291,456 el
    bf16* xn2 = xw;
    bf16* h1  = qb;                    // [T,384] bf16 spans qb+kb
    float* x1 = out;

    cvt_kernel<<<108, 256, 0, stream>>>(qkvw, wq, 110592);
    cvt_kernel<<<36, 256, 0, stream>>>(projw, wp, 36864);
    cvt_kernel<<<72, 256, 0, stream>>>(fc1w, w1, 73728);
    cvt_kernel<<<72, 256, 0, stream>>>(fc2w, w2, 73728);
    bm_kernel<<<1536, 256, 0, stream>>>(rpb, rel, amask, bmT);
    ln_kernel<<<32768, 256, 0, stream>>>(x, n1g, n1b, xw, 1);
    qkv_gemm<<<2048, 256, 0, stream>>>(xw, wq, qkvb, qb, kb, vtb);
    attn_kernel<<<3072, 256, 0, stream>>>(qb, kb, vtb, bmT, xw);
    proj_gemm<<<2048, 256, 0, stream>>>(xw, wp, projb, x, x1);
    ln_kernel<<<32768, 256, 0, stream>>>(x1, n2g, n2b, xn2, 0);
    fc1_gemm<<<2048, 256, 0, stream>>>(xn2, w1, fc1b, h1);
    fc2_gemm<<<2048, 256, 0, stream>>>(h1, w2, fc2b, x1, out);
}

// Round 4
// 729.576 us; speedup vs baseline: 2.2152x; 1.1109x over previous
//
#include <hip/hip_runtime.h>
#include <hip/hip_bf16.h>

// Swin block, B=8 H=W=128 C=192 HEADS=6 WS=8 SS=4 MLP_H=384
// T = 131072 tokens, 2048 windows (256/batch), N=64, hd=32. I/O f32.
//
// r4: traffic-minimized fused pipeline, residual stream kept in WINDOWED order:
//   setup: fold LN gammas into W (qkv,fc1), betas into biases; cvt others; bmT
//   1. qkv_ln : gather x (perm) + in-register LN1 -> q,k [wh][n][32], vt [wh][32][64]
//   2. attn   : MFMA attention -> ao [wh][n][32] (1/l folded into P)
//   3. proj_ln: proj GEMM + residual(x perm) -> x1w f32 [o][192] coalesced,
//               + fused LN2 (cross-wave LDS reduce) -> xn2 bf16 [o][192]
//   4. mlp    : fc1+GELU (h in LDS) + fc2 + residual, scatter to d_out (perm)

typedef __hip_bfloat16 bf16;
typedef __bf16 bf16x8 __attribute__((ext_vector_type(8)));
typedef float f32x4 __attribute__((ext_vector_type(4)));

static __device__ __forceinline__ bf16x8 ldg8(const bf16* p) {
    return *reinterpret_cast<const bf16x8*>(p);
}

// -------- setup: dst[f*K+c] = bf16(src[f*K+c] * g[c]), g==nullptr -> plain ----
__global__ __launch_bounds__(256) void cvt_scale_kernel(
    const float* __restrict__ src, const float* __restrict__ g,
    bf16* __restrict__ dst, int n, int K)
{
    int i = (blockIdx.x * 256 + threadIdx.x) * 4;
    if (i < n) {
        float4 v = *reinterpret_cast<const float4*>(src + i);
        int c = i % K;
        if (g) { v.x *= g[c]; v.y *= g[c + 1]; v.z *= g[c + 2]; v.w *= g[c + 3]; }
        dst[i]     = __float2bfloat16(v.x);
        dst[i + 1] = __float2bfloat16(v.y);
        dst[i + 2] = __float2bfloat16(v.z);
        dst[i + 3] = __float2bfloat16(v.w);
    }
}

// -------- setup: bout[f] = b0[f] + sum_c beta[c] * W[f*K+c]  (one wave per f) ---
__global__ __launch_bounds__(64) void bias_fold_kernel(
    const float* __restrict__ b0, const float* __restrict__ W,
    const float* __restrict__ beta, float* __restrict__ bout, int K)
{
    int f = blockIdx.x, lane = threadIdx.x;
    float s = 0.f;
    for (int c = lane; c < K; c += 64) s += beta[c] * W[(size_t)f * K + c];
#pragma unroll
    for (int off = 32; off; off >>= 1) s += __shfl_xor(s, off, 64);
    if (lane == 0) bout[f] = b0[f] + s;
}

// -------- setup: bias+mask table, TRANSPOSED: bmT[wm][head][n_k][n_q] ----------
__global__ __launch_bounds__(256) void bm_kernel(
    const float* __restrict__ rpb, const int* __restrict__ rel,
    const float* __restrict__ amask, bf16* __restrict__ bmT)
{
    int wm = blockIdx.x / 6, head = blockIdx.x % 6;
    const float* mrow = amask + (size_t)wm * 4096;
    bf16* o = bmT + (size_t)blockIdx.x * 4096;
    for (int idx = threadIdx.x; idx < 4096; idx += 256) {
        int nk = idx >> 6, nq = idx & 63;
        int t = nq * 64 + nk;
        o[idx] = __float2bfloat16(rpb[rel[t] * 6 + head] + mrow[t]);
    }
}

// ---------------- QKV + fused LN1 ----------------
// block 256 = 4 waves; win = blockIdx; gathers x rows (shift+window perm),
// LN in-register (gamma/beta folded into W/bias), then r3 GEMM structure.
__global__ __launch_bounds__(256) void qkv_ln(
    const float* __restrict__ x, const bf16* __restrict__ W,
    const float* __restrict__ bias, bf16* __restrict__ q,
    bf16* __restrict__ k, bf16* __restrict__ vt)
{
    int wave = threadIdx.x >> 6, lane = threadIdx.x & 63;
    int quad = lane >> 4, l16 = lane & 15;
    int win = blockIdx.x;
    int b = win >> 8, wrem = win & 255, wr = wrem >> 4, wc = wrem & 15;
    bf16x8 a[4][6];
#pragma unroll
    for (int mt = 0; mt < 4; ++mt) {
        int n = mt * 16 + l16;
        int ii = n >> 3, jj = n & 7;
        int h = (wr * 8 + ii + 4) & 127, w2 = (wc * 8 + jj + 4) & 127;
        const float* xp = x + ((size_t)b * 16384 + h * 128 + w2) * 192 + quad * 8;
        float e[48];
        float sum = 0.f, sq = 0.f;
#pragma unroll
        for (int kk = 0; kk < 6; ++kk) {
            float4 u0 = *reinterpret_cast<const float4*>(xp + kk * 32);
            float4 u1 = *reinterpret_cast<const float4*>(xp + kk * 32 + 4);
            e[kk * 8 + 0] = u0.x; e[kk * 8 + 1] = u0.y; e[kk * 8 + 2] = u0.z; e[kk * 8 + 3] = u0.w;
            e[kk * 8 + 4] = u1.x; e[kk * 8 + 5] = u1.y; e[kk * 8 + 6] = u1.z; e[kk * 8 + 7] = u1.w;
#pragma unroll
            for (int j = 0; j < 8; ++j) { float v = e[kk * 8 + j]; sum += v; sq += v * v; }
        }
        sum += __shfl_xor(sum, 16, 64); sum += __shfl_xor(sum, 32, 64);
        sq  += __shfl_xor(sq, 16, 64);  sq  += __shfl_xor(sq, 32, 64);
        float mean = sum * (1.f / 192.f);
        float rstd = rsqrtf(sq * (1.f / 192.f) - mean * mean + 1e-5f);
#pragma unroll
        for (int kk = 0; kk < 6; ++kk)
#pragma unroll
            for (int j = 0; j < 8; ++j)
                a[mt][kk][j] = (__bf16)((e[kk * 8 + j] - mean) * rstd);
    }
#pragma unroll 1
    for (int i = 0; i < 9; ++i) {
        int nt = wave * 9 + i;
        const bf16* wrow = W + (size_t)(nt * 16 + l16) * 192 + quad * 8;
        bf16x8 bfr[6];
#pragma unroll
        for (int kk = 0; kk < 6; ++kk) bfr[kk] = ldg8(wrow + kk * 32);
        f32x4 acc[4];
#pragma unroll
        for (int mt = 0; mt < 4; ++mt) {
            f32x4 z = {0.f, 0.f, 0.f, 0.f};
#pragma unroll
            for (int kk = 0; kk < 6; ++kk)
                z = __builtin_amdgcn_mfma_f32_16x16x32_bf16(a[mt][kk], bfr[kk], z, 0, 0, 0);
            acc[mt] = z;
        }
        int f = nt * 16 + l16;
        float bb = bias[f];
        int which = f / 192;
        int head = (f % 192) >> 5;
        int d = f & 31;
        float sc = (which == 0) ? 0.17677669529663687f : 1.f;
        size_t wh2 = (size_t)(win * 6 + head) * 2048;
#pragma unroll
        for (int mt = 0; mt < 4; ++mt) {
#pragma unroll
            for (int r = 0; r < 4; ++r) {
                int n = mt * 16 + quad * 4 + r;
                bf16 val = __float2bfloat16((acc[mt][r] + bb) * sc);
                if (which == 2)      vt[wh2 + d * 64 + n] = val;
                else if (which == 1) k[wh2 + n * 32 + d] = val;
                else                 q[wh2 + n * 32 + d] = val;
            }
        }
    }
}

// ---------------- Attention (MFMA): one wave per (win, head) ----------------
__global__ __launch_bounds__(256) void attn_kernel(
    const bf16* __restrict__ q, const bf16* __restrict__ k,
    const bf16* __restrict__ vt, const bf16* __restrict__ bmT,
    bf16* __restrict__ ao)
{
    __shared__ __align__(16) bf16 lds[4][64 * 72];
    int wave = threadIdx.x >> 6, lane = threadIdx.x & 63;
    int quad = lane >> 4, l16 = lane & 15;
    int wh = blockIdx.x * 4 + wave;
    int win = wh / 6, head = wh - win * 6;
    const bf16* Qp = q + (size_t)wh * 2048;
    const bf16* Kp = k + (size_t)wh * 2048;
    const bf16* Vp = vt + (size_t)wh * 2048;
    const bf16* bm = bmT + (size_t)((win & 255) * 6 + head) * 4096;

    bf16x8 kf[4], qf[4];
#pragma unroll
    for (int t = 0; t < 4; ++t) {
        kf[t] = ldg8(Kp + (t * 16 + l16) * 32 + quad * 8);
        qf[t] = ldg8(Qp + (t * 16 + l16) * 32 + quad * 8);
    }
    f32x4 s[4][4];
#pragma unroll
    for (int mt = 0; mt < 4; ++mt)
#pragma unroll
        for (int nt = 0; nt < 4; ++nt) {
            f32x4 z = {0.f, 0.f, 0.f, 0.f};
            s[mt][nt] = __builtin_amdgcn_mfma_f32_16x16x32_bf16(kf[mt], qf[nt], z, 0, 0, 0);
        }
#pragma unroll
    for (int mt = 0; mt < 4; ++mt)
#pragma unroll
        for (int nt = 0; nt < 4; ++nt)
#pragma unroll
            for (int r = 0; r < 4; ++r) {
                int nk = mt * 16 + quad * 4 + r, nq = nt * 16 + l16;
                s[mt][nt][r] += __bfloat162float(bm[nk * 64 + nq]);
            }
    float linv[4];
#pragma unroll
    for (int nt = 0; nt < 4; ++nt) {
        float mx = -3.0e38f;
#pragma unroll
        for (int mt = 0; mt < 4; ++mt)
#pragma unroll
            for (int r = 0; r < 4; ++r) mx = fmaxf(mx, s[mt][nt][r]);
        mx = fmaxf(mx, __shfl_xor(mx, 16, 64));
        mx = fmaxf(mx, __shfl_xor(mx, 32, 64));
        float sum = 0.f;
#pragma unroll
        for (int mt = 0; mt < 4; ++mt)
#pragma unroll
            for (int r = 0; r < 4; ++r) {
                float p = __expf(s[mt][nt][r] - mx);
                s[mt][nt][r] = p;
                sum += p;
            }
        sum += __shfl_xor(sum, 16, 64);
        sum += __shfl_xor(sum, 32, 64);
        linv[nt] = 1.f / sum;
    }
    // write P[n_q][n_k] * (1/l) to LDS (stride 72)
    bf16* lp = lds[wave];
#pragma unroll
    for (int mt = 0; mt < 4; ++mt)
#pragma unroll
        for (int nt = 0; nt < 4; ++nt)
#pragma unroll
            for (int r = 0; r < 4; ++r)
                lp[(nt * 16 + l16) * 72 + mt * 16 + quad * 4 + r] =
                    __float2bfloat16(s[mt][nt][r] * linv[nt]);
    f32x4 o[4][2];
#pragma unroll
    for (int mo = 0; mo < 4; ++mo)
#pragma unroll
        for (int no = 0; no < 2; ++no) o[mo][no] = (f32x4){0.f, 0.f, 0.f, 0.f};
#pragma unroll
    for (int kh = 0; kh < 2; ++kh) {
        bf16x8 pf[4];
#pragma unroll
        for (int mo = 0; mo < 4; ++mo)
            pf[mo] = *reinterpret_cast<const bf16x8*>(
                lp + (mo * 16 + l16) * 72 + kh * 32 + quad * 8);
#pragma unroll
        for (int no = 0; no < 2; ++no) {
            bf16x8 vf = ldg8(Vp + (no * 16 + l16) * 64 + kh * 32 + quad * 8);
#pragma unroll
            for (int mo = 0; mo < 4; ++mo)
                o[mo][no] = __builtin_amdgcn_mfma_f32_16x16x32_bf16(pf[mo], vf, o[mo][no], 0, 0, 0);
        }
    }
    // store to ao[wh][n][32]
    bf16* ob = ao + (size_t)wh * 2048;
#pragma unroll
    for (int mo = 0; mo < 4; ++mo)
#pragma unroll
        for (int r = 0; r < 4; ++r) {
            int nq = mo * 16 + quad * 4 + r;
            ob[nq * 32 + l16]      = __float2bfloat16(o[mo][0][r]);
            ob[nq * 32 + 16 + l16] = __float2bfloat16(o[mo][1][r]);
        }
}

// --------- Proj GEMM + residual (x gathered) + fused LN2 -> x1w f32, xn2 bf16 ----
__global__ __launch_bounds__(256) void proj_ln(
    const bf16* __restrict__ ao, const bf16* __restrict__ W,
    const float* __restrict__ pb, const float* __restrict__ x,
    float* __restrict__ x1w, bf16* __restrict__ xn2)
{
    __shared__ float part[4][64], part2[4][64], ms[64][2];
    int wave = threadIdx.x >> 6, lane = threadIdx.x & 63;
    int quad = lane >> 4, l16 = lane & 15;
    int win = blockIdx.x;
    int b = win >> 8, wrem = win & 255, wr = wrem >> 4, wc = wrem & 15;
    bf16x8 a[4][6];
#pragma unroll
    for (int mt = 0; mt < 4; ++mt)
#pragma unroll
        for (int h = 0; h < 6; ++h)
            a[mt][h] = ldg8(ao + (size_t)(win * 6 + h) * 2048 + (mt * 16 + l16) * 32 + quad * 8);
    f32x4 z[3][4];
#pragma unroll 1
    for (int i = 0; i < 3; ++i) {
        int nt = wave * 3 + i;
        const bf16* wp = W + (size_t)(nt * 16 + l16) * 192 + quad * 8;
        bf16x8 bfr[6];
#pragma unroll
        for (int kk = 0; kk < 6; ++kk) bfr[kk] = ldg8(wp + kk * 32);
        f32x4 zz = {0.f, 0.f, 0.f, 0.f};
#pragma unroll
        for (int mt = 0; mt < 4; ++mt) {
            zz = (f32x4){0.f, 0.f, 0.f, 0.f};
#pragma unroll
            for (int kk = 0; kk < 6; ++kk)
                zz = __builtin_amdgcn_mfma_f32_16x16x32_bf16(a[mt][kk], bfr[kk], zz, 0, 0, 0);
            z[i][mt] = zz;
        }
    }
    // x1 = x_perm + proj + pb; accumulate in z; per-row partial stats
#pragma unroll
    for (int i = 0; i < 3; ++i) {
        int c = (wave * 3 + i) * 16 + l16;
        float bb = pb[c];
#pragma unroll
        for (int mt = 0; mt < 4; ++mt)
#pragma unroll
            for (int r = 0; r < 4; ++r) {
                int n = mt * 16 + quad * 4 + r;
                int ii = n >> 3, jj = n & 7;
                int h = (wr * 8 + ii + 4) & 127, w2 = (wc * 8 + jj + 4) & 127;
                size_t sidx = ((size_t)b * 16384 + h * 128 + w2) * 192 + c;
                z[i][mt][r] += bb + x[sidx];
            }
    }
#pragma unroll
    for (int mt = 0; mt < 4; ++mt)
#pragma unroll
        for (int r = 0; r < 4; ++r) {
            float s1 = 0.f, s2 = 0.f;
#pragma unroll
            for (int i = 0; i < 3; ++i) {
                float v = z[i][mt][r];
                s1 += v; s2 += v * v;
            }
#pragma unroll
            for (int off = 1; off < 16; off <<= 1) {
                s1 += __shfl_xor(s1, off, 64);
                s2 += __shfl_xor(s2, off, 64);
            }
            if (l16 == 0) {
                int row = mt * 16 + quad * 4 + r;
                part[wave][row] = s1;
                part2[wave][row] = s2;
            }
        }
    __syncthreads();
    if (threadIdx.x < 64) {
        int t = threadIdx.x;
        float S = part[0][t] + part[1][t] + part[2][t] + part[3][t];
        float S2 = part2[0][t] + part2[1][t] + part2[2][t] + part2[3][t];
        float m = S * (1.f / 192.f);
        ms[t][0] = m;
        ms[t][1] = rsqrtf(S2 * (1.f / 192.f) - m * m + 1e-5f);
    }
    __syncthreads();
#pragma unroll
    for (int i = 0; i < 3; ++i) {
        int c = (wave * 3 + i) * 16 + l16;
#pragma unroll
        for (int mt = 0; mt < 4; ++mt)
#pragma unroll
            for (int r = 0; r < 4; ++r) {
                int row = mt * 16 + quad * 4 + r;
                size_t o = (size_t)win * 64 + row;
                float v = z[i][mt][r];
                x1w[o * 192 + c] = v;
                xn2[o * 192 + c] = __float2bfloat16((v - ms[row][0]) * ms[row][1]);
            }
    }
}

// --------- MLP fused: fc1 (+LN2-folded W/b) + exact GELU + fc2 + residual -------
// h tile [64][384] in LDS (stride 392); final store scattered to d_out (perm).
__global__ __launch_bounds__(256) void mlp_kernel(
    const bf16* __restrict__ xn2, const bf16* __restrict__ W1,
    const float* __restrict__ b1, const bf16* __restrict__ W2,
    const float* __restrict__ b2, const float* __restrict__ x1w,
    float* __restrict__ out)
{
    __shared__ __align__(16) bf16 hsh[64 * 392];
    int wave = threadIdx.x >> 6, lane = threadIdx.x & 63;
    int quad = lane >> 4, l16 = lane & 15;
    int win = blockIdx.x;
    size_t mbase = (size_t)win * 64;
    int b = win >> 8, wrem = win & 255, wr = wrem >> 4, wc = wrem & 15;
    bf16x8 a[4][6];
#pragma unroll
    for (int mt = 0; mt < 4; ++mt) {
        const bf16* ar = xn2 + (mbase + mt * 16 + l16) * 192 + quad * 8;
#pragma unroll
        for (int kk = 0; kk < 6; ++kk) a[mt][kk] = ldg8(ar + kk * 32);
    }
#pragma unroll 1
    for (int i = 0; i < 6; ++i) {
        int nt = wave * 6 + i;
        const bf16* wp = W1 + (size_t)(nt * 16 + l16) * 192 + quad * 8;
        bf16x8 bfr[6];
#pragma unroll
        for (int kk = 0; kk < 6; ++kk) bfr[kk] = ldg8(wp + kk * 32);
        float bb = b1[nt * 16 + l16];
#pragma unroll
        for (int mt = 0; mt < 4; ++mt) {
            f32x4 zz = {0.f, 0.f, 0.f, 0.f};
#pragma unroll
            for (int kk = 0; kk < 6; ++kk)
                zz = __builtin_amdgcn_mfma_f32_16x16x32_bf16(a[mt][kk], bfr[kk], zz, 0, 0, 0);
#pragma unroll
            for (int r = 0; r < 4; ++r) {
                float val = zz[r] + bb;
                float gl = 0.5f * val * (1.f + erff(val * 0.70710678118654752f));
                hsh[(mt * 16 + quad * 4 + r) * 392 + nt * 16 + l16] = __float2bfloat16(gl);
            }
        }
    }
    __syncthreads();
#pragma unroll 1
    for (int mt = 0; mt < 4; ++mt) {
        bf16x8 pa[12];
#pragma unroll
        for (int kk = 0; kk < 12; ++kk)
            pa[kk] = *reinterpret_cast<const bf16x8*>(
                hsh + (mt * 16 + l16) * 392 + kk * 32 + quad * 8);
#pragma unroll 1
        for (int j = 0; j < 3; ++j) {
            int nt = wave * 3 + j;
            const bf16* wp = W2 + (size_t)(nt * 16 + l16) * 384 + quad * 8;
            f32x4 zz = {0.f, 0.f, 0.f, 0.f};
#pragma unroll
            for (int kk = 0; kk < 12; ++kk) {
                bf16x8 bfr = ldg8(wp + kk * 32);
                zz = __builtin_amdgcn_mfma_f32_16x16x32_bf16(pa[kk], bfr, zz, 0, 0, 0);
            }
            int c = nt * 16 + l16;
            float bb = b2[c];
#pragma unroll
            for (int r = 0; r < 4; ++r) {
                int row = mt * 16 + quad * 4 + r;
                int ii = row >> 3, jj = row & 7;
                int h = (wr * 8 + ii + 4) & 127, w2 = (wc * 8 + jj + 4) & 127;
                size_t didx = ((size_t)b * 16384 + h * 128 + w2) * 192 + c;
                out[didx] = zz[r] + bb + x1w[(mbase + row) * 192 + c];
            }
        }
    }
}

extern "C" void kernel_launch(void* const* d_in, const int* in_sizes, int n_in,
                              void* d_out, int out_size, void* d_ws, size_t ws_size,
                              hipStream_t stream)
{
    const float* x     = (const float*)d_in[0];
    const float* n1g   = (const float*)d_in[1];
    const float* n1b   = (const float*)d_in[2];
    const float* qkvw  = (const float*)d_in[3];
    const float* qkvb  = (const float*)d_in[4];
    const float* rpb   = (const float*)d_in[5];
    const float* projw = (const float*)d_in[6];
    const float* projb = (const float*)d_in[7];
    const float* n2g   = (const float*)d_in[8];
    const float* n2b   = (const float*)d_in[9];
    const float* fc1w  = (const float*)d_in[10];
    const float* fc1b  = (const float*)d_in[11];
    const float* fc2w  = (const float*)d_in[12];
    const float* fc2b  = (const float*)d_in[13];
    const int*   rel   = (const int*)d_in[14];
    const float* amask = (const float*)d_in[15];
    float* out = (float*)d_out;

    char* ws = (char*)d_ws;
    const size_t SZ = (size_t)131072 * 192 * 2;   // 50,331,648 B per bf16 [T,192]
    bf16* qb  = (bf16*)(ws);                       // q   ; later x1w low half
    bf16* kb  = (bf16*)(ws + SZ);                  // k   ; later x1w high half
    bf16* vtb = (bf16*)(ws + 2 * SZ);              // vt  ; later xn2
    bf16* aob = (bf16*)(ws + 3 * SZ);              // attention out
    char* wreg = ws + 4 * SZ;
    bf16*  wq  = (bf16*)(wreg);                    // 110592 el
    bf16*  wp  = wq + 110592;                      // 36864
    bf16*  w1  = wp + 36864;                       // 73728
    bf16*  w2  = w1 + 73728;                       // 73728
    float* bq  = (float*)(w2 + 73728);             // 576 f32
    float* b1  = bq + 576;                         // 384 f32
    bf16*  bmT = (bf16*)(b1 + 384);                // 6,291,456 el (12.6 MB)
    float* x1w = (float*)(ws);                     // f32 [T,192] over q+k (dead)
    bf16*  xn2 = vtb;                              // over vt (dead)

    // setup (tiny)
    cvt_scale_kernel<<<108, 256, 0, stream>>>(qkvw, n1g, wq, 110592, 192);
    cvt_scale_kernel<<<36, 256, 0, stream>>>(projw, nullptr, wp, 36864, 192);
    cvt_scale_kernel<<<72, 256, 0, stream>>>(fc1w, n2g, w1, 73728, 192);
    cvt_scale_kernel<<<72, 256, 0, stream>>>(fc2w, nullptr, w2, 73728, 384);
    bias_fold_kernel<<<576, 64, 0, stream>>>(qkvb, qkvw, n1b, bq, 192);
    bias_fold_kernel<<<384, 64, 0, stream>>>(fc1b, fc1w, n2b, b1, 192);
    bm_kernel<<<1536, 256, 0, stream>>>(rpb, rel, amask, bmT);
    // main pipeline
    qkv_ln<<<2048, 256, 0, stream>>>(x, wq, bq, qb, kb, vtb);
    attn_kernel<<<3072, 256, 0, stream>>>(qb, kb, vtb, bmT, aob);
    proj_ln<<<2048, 256, 0, stream>>>(aob, wp, projb, x, x1w, xn2);
    mlp_kernel<<<2048, 256, 0, stream>>>(xn2, w1, b1, w2, fc2b, x1w, out);
}